// Round 2
// baseline (214.000 us; speedup 1.0000x reference)
//
#include <hip/hip_runtime.h>
#include <hip/hip_bf16.h>
#include <math.h>

// Shapes: B=8, T1=512, T2=128, LA=128, E=64, G=3E=192, DL=256
#define Bn 8
#define T1n 512
#define T2n 128
#define En 64
#define Gn 192
#define DLn 256

// LDS-only barrier: no vmcnt drain (HIP __syncthreads drains vmcnt(0), which
// would stall on our prefetched global loads + fire-and-forget ctx stores).
__device__ __forceinline__ void bar_lds() {
    asm volatile("s_waitcnt lgkmcnt(0)\n\ts_barrier" ::: "memory");
}

// ---------------------------------------------------------------------------
// K1: xg[d][b][t][j] = b_d[0][j] + sum_e emb_table[char_seq[b][t]][e] * K_d[e][j]
// grid: B*T2 = 1024 blocks, 384 threads (2 dirs x 192 gates)
// ---------------------------------------------------------------------------
__global__ __launch_bounds__(384) void k_xg(const int* __restrict__ char_seq,
                                            const float* __restrict__ emb_table,
                                            const float* __restrict__ Kf,
                                            const float* __restrict__ bf,
                                            const float* __restrict__ Kb,
                                            const float* __restrict__ bb,
                                            float* __restrict__ xg) {
    int bt = blockIdx.x;              // 0..1023
    int b = bt >> 7, t = bt & 127;
    int tid = threadIdx.x;            // 0..383
    __shared__ __align__(16) float emb[En];
    if (tid < En) {
        int cs = char_seq[b * T2n + t];
        emb[tid] = emb_table[cs * En + tid];
    }
    __syncthreads();
    int d = tid / Gn;                 // wave-uniform (192 = 3 waves)
    int j = tid - d * Gn;
    const float* K = d ? Kb : Kf;
    const float* bias = d ? bb : bf;  // row 0
    float acc = bias[j];
    #pragma unroll
    for (int e = 0; e < En; ++e) acc = fmaf(emb[e], K[e * Gn + j], acc);
    xg[((d * Bn + b) * T2n + t) * Gn + j] = acc;
}

// ---------------------------------------------------------------------------
// K2: sL[b][t] = dot(lstm[b][t][:], w_char[0:256])
// ---------------------------------------------------------------------------
__global__ __launch_bounds__(256) void k_sL(const float* __restrict__ lstm,
                                            const float* __restrict__ w_char,
                                            float* __restrict__ sL) {
    int wave = threadIdx.x >> 6;
    int lane = threadIdx.x & 63;
    int bt = blockIdx.x * 4 + wave;   // 0..4095
    const float4* row = (const float4*)(lstm + (size_t)bt * DLn);
    const float4* wl  = (const float4*)(w_char);
    float4 r = row[lane];
    float4 w = wl[lane];
    float s = r.x * w.x + r.y * w.y + r.z * w.z + r.w * w.w;
    #pragma unroll
    for (int off = 32; off; off >>= 1) s += __shfl_down(s, off);
    if (lane == 0) sL[bt] = s;
}

// ---------------------------------------------------------------------------
// K3: sequential GRU scan, v2.
// grid: 16 blocks = (b, dir), 384 threads = 6 waves.
// Threads split the h.R dot 2-way: p = tid/192 owns k in [32p,32p+32),
// j = tid%192 owns gate column j. Partial sums combined by the gate wave.
// Global xg loads are prefetched 3 steps deep; barriers are LDS-only so the
// prefetch (and the per-step ctx global stores) never get drained.
// ---------------------------------------------------------------------------
__global__ __launch_bounds__(384) void k_scan(const float* __restrict__ xg,
                                              const float* __restrict__ Rf,
                                              const float* __restrict__ bf,
                                              const float* __restrict__ Rb,
                                              const float* __restrict__ bb,
                                              const int* __restrict__ char_seq,
                                              float* __restrict__ ctx) {
    int blk = blockIdx.x;             // 0..15
    int b = blk & 7, d = blk >> 3;
    int tid = threadIdx.x;            // 0..383
    int p = tid >= Gn;                // wave-uniform (waves 0-2: p=0, 3-5: p=1)
    int j = p ? tid - Gn : tid;       // 0..191
    const float* R = d ? Rb : Rf;
    const float* bias = (d ? bb : bf) + Gn;   // b[1]
    int k0 = p << 5;                  // 0 or 32
    float Rcol[32];
    #pragma unroll
    for (int k = 0; k < 32; ++k) Rcol[k] = R[(k0 + k) * Gn + j];
    float accinit = p ? 0.f : bias[j];

    __shared__ __align__(16) float h[En];
    __shared__ float rg2[2][Gn];
    __shared__ float xrow[Gn];
    __shared__ int mloc[T2n];
    if (tid < En) h[tid] = 0.f;
    if (tid < T2n) mloc[tid] = char_seq[b * T2n + tid];
    float hreg = 0.f, y = 0.f;
    const float* xgbase = xg + (size_t)(d * Bn + b) * T2n * Gn;
    float* ctxbase = ctx + (size_t)b * T2n * 128 + d * En;

    // prefetch pipeline, depth 3 (only p==0 waves load; ~1000+ cyc of cover)
    int i0 = d ? (T2n - 1) : 0;
    int istep = d ? -1 : 1;
    float xt0 = 0.f, xt1 = 0.f, xt2 = 0.f;
    if (!p) {
        xt0 = xgbase[i0 * Gn + j];
        xt1 = xgbase[(i0 + istep) * Gn + j];
        xt2 = xgbase[(i0 + 2 * istep) * Gn + j];
    }
    __syncthreads();    // full barrier once (h/mloc init; no loads in flight we mind)

    for (int step = 0; step < T2n; ++step) {
        int idx = i0 + istep * step;
        float xt3 = 0.f;
        if (!p) {
            int sp = step + 3; if (sp >= T2n) sp = T2n - 1;
            xt3 = xgbase[(i0 + istep * sp) * Gn + j];
        }
        // partial dot over 32 elements of h, 4 accumulator chains
        const float4* h4 = (const float4*)(h + k0);
        float a0 = accinit, a1 = 0.f, a2 = 0.f, a3 = 0.f;
        #pragma unroll
        for (int q = 0; q < 8; ++q) {
            float4 hv = h4[q];
            a0 = fmaf(hv.x, Rcol[4 * q + 0], a0);
            a1 = fmaf(hv.y, Rcol[4 * q + 1], a1);
            a2 = fmaf(hv.z, Rcol[4 * q + 2], a2);
            a3 = fmaf(hv.w, Rcol[4 * q + 3], a3);
        }
        rg2[p][j] = (a0 + a1) + (a2 + a3);
        if (!p) xrow[j] = xt0;        // vmcnt wait targets only this 3-old load
        bar_lds();
        if (tid < En) {
            float xz = xrow[tid], xr = xrow[En + tid], xh = xrow[2 * En + tid];
            float rz = rg2[0][tid] + rg2[1][tid];
            float rr = rg2[0][En + tid] + rg2[1][En + tid];
            float rh = rg2[0][2 * En + tid] + rg2[1][2 * En + tid];
            float z = 1.f / (1.f + __expf(-(xz + rz)));
            float r = 1.f / (1.f + __expf(-(xr + rr)));
            float hh = tanhf(xh + r * rh);
            float hn = z * hreg + (1.f - z) * hh;
            if (mloc[idx] != 0) { hreg = hn; y = hn; }
            h[tid] = hreg;
            ctxbase[idx * 128 + tid] = y;   // fire-and-forget; never drained
        }
        bar_lds();
        xt0 = xt1; xt1 = xt2; xt2 = xt3;
    }
}

// ---------------------------------------------------------------------------
// K4: per (b,s): P0/P1 = ctx_row @ W1[tap], then
//   A  = P0@W20, Cm = P1@W21, Bm = P1@W20 + P0@W21, and sC = ctx_row . w_c
// ---------------------------------------------------------------------------
__global__ __launch_bounds__(128) void k_ctxw(const float* __restrict__ ctx,
                                              const float* __restrict__ conv1_w,
                                              const float* __restrict__ conv2_w,
                                              const float* __restrict__ w_char,
                                              float* __restrict__ Am,
                                              float* __restrict__ Bm,
                                              float* __restrict__ Cm,
                                              float* __restrict__ sC) {
    int bs = blockIdx.x;              // b*128+s
    int tid = threadIdx.x;            // 0..127
    __shared__ float crow[128];
    __shared__ float p0[En], p1[En];
    crow[tid] = ctx[(size_t)bs * 128 + tid];
    __syncthreads();
    if (tid < 64) {
        float s = crow[tid] * w_char[DLn + tid] + crow[64 + tid] * w_char[DLn + 64 + tid];
        #pragma unroll
        for (int off = 32; off; off >>= 1) s += __shfl_down(s, off);
        if (tid == 0) sC[bs] = s;
    }
    int tap = tid >> 6, o = tid & 63;
    const float* W = conv1_w + tap * 128 * En;
    float acc = 0.f;
    #pragma unroll
    for (int c = 0; c < 128; ++c) acc = fmaf(crow[c], W[c * En + o], acc);
    if (tap == 0) p0[o] = acc; else p1[o] = acc;
    __syncthreads();
    const float* W20 = conv2_w;            // [64][64]
    const float* W21 = conv2_w + En * En;
    if (tid < 64) {
        float a = 0.f, cm = 0.f;
        #pragma unroll
        for (int c = 0; c < En; ++c) {
            a  = fmaf(p0[c], W20[c * En + tid], a);
            cm = fmaf(p1[c], W21[c * En + tid], cm);
        }
        Am[(size_t)bs * En + tid] = a;
        Cm[(size_t)bs * En + tid] = cm;
    } else {
        int o2 = tid - 64;
        float bacc = 0.f;
        #pragma unroll
        for (int c = 0; c < En; ++c) {
            bacc = fmaf(p1[c], W20[c * En + o2], bacc);
            bacc = fmaf(p0[c], W21[c * En + o2], bacc);
        }
        Bm[(size_t)bs * En + o2] = bacc;
    }
}

// ---------------------------------------------------------------------------
// K5: per (b, 8-t tile): score rows -> char_weights; then
//   fe[b,t,o] = max_s ( sc[s]*A[s,o] + sc[s+1]*Bm[s+1,o] + sc[s+2]*Cm[s+2,o] + bb2[o] )
// ---------------------------------------------------------------------------
__global__ __launch_bounds__(128) void k_final(const float* __restrict__ sL,
                                               const float* __restrict__ sC,
                                               const float* __restrict__ w_char,
                                               const float* __restrict__ b_char,
                                               const float* __restrict__ conv1_b,
                                               const float* __restrict__ conv2_w,
                                               const float* __restrict__ conv2_b,
                                               const float* __restrict__ Am,
                                               const float* __restrict__ Bm,
                                               const float* __restrict__ Cm,
                                               float* __restrict__ fe,
                                               float* __restrict__ cw) {
    int blk = blockIdx.x;             // b(3b) x ttile(6b)
    int b = blk >> 6, ttile = blk & 63;
    int t0 = ttile * 8;
    int tid = threadIdx.x;            // 0..127
    float w_t = w_char[DLn + 128], w_i = w_char[DLn + 129], bc = b_char[0];
    __shared__ float sc8[8][T2n];
    {
        int s = tid;
        float sCs = sC[b * T2n + s] + w_i * (float)s + bc;
        #pragma unroll
        for (int tt = 0; tt < 8; ++tt) {
            int t = t0 + tt;
            float v = sL[b * T1n + t] + sCs + w_t * (float)t;
            sc8[tt][s] = v;
            cw[((size_t)(b * T1n + t)) * T2n + s] = v;
        }
    }
    int o = tid & 63, p = tid >> 6;
    float bb2 = conv2_b[o];
    #pragma unroll
    for (int c = 0; c < En; ++c)
        bb2 += conv1_b[c] * (conv2_w[c * En + o] + conv2_w[En * En + c * En + o]);
    __syncthreads();

    float acc[8];
    #pragma unroll
    for (int tt = 0; tt < 8; ++tt) acc[tt] = -__builtin_inff();
    const float* Ab = Am + (size_t)(b * T2n) * En + o;
    const float* Bb = Bm + (size_t)(b * T2n) * En + o;
    const float* Cb = Cm + (size_t)(b * T2n) * En + o;
    for (int s = p; s < T2n - 2; s += 2) {
        float a  = Ab[s * En];
        float bm = Bb[(s + 1) * En];
        float cm = Cb[(s + 2) * En];
        #pragma unroll
        for (int tt = 0; tt < 8; ++tt) {
            float v = fmaf(sc8[tt][s], a,
                      fmaf(sc8[tt][s + 1], bm,
                      fmaf(sc8[tt][s + 2], cm, bb2)));
            acc[tt] = fmaxf(acc[tt], v);
        }
    }
    __shared__ float red[64][9];
    if (p == 1) {
        #pragma unroll
        for (int tt = 0; tt < 8; ++tt) red[o][tt] = acc[tt];
    }
    __syncthreads();
    if (p == 0) {
        #pragma unroll
        for (int tt = 0; tt < 8; ++tt) {
            float v = fmaxf(acc[tt], red[o][tt]);
            fe[((size_t)(b * T1n + t0 + tt)) * En + o] = v;
        }
    }
}

// ---------------------------------------------------------------------------
extern "C" void kernel_launch(void* const* d_in, const int* in_sizes, int n_in,
                              void* d_out, int out_size, void* d_ws, size_t ws_size,
                              hipStream_t stream) {
    const float* lstm      = (const float*)d_in[0];
    const int*   char_seq  = (const int*)d_in[1];
    const float* emb_table = (const float*)d_in[2];
    const float* Kf        = (const float*)d_in[3];
    const float* Rf        = (const float*)d_in[4];
    const float* bf        = (const float*)d_in[5];
    const float* Kb        = (const float*)d_in[6];
    const float* Rb        = (const float*)d_in[7];
    const float* bb        = (const float*)d_in[8];
    const float* w_char    = (const float*)d_in[9];
    const float* b_char    = (const float*)d_in[10];
    const float* conv1_w   = (const float*)d_in[11];
    const float* conv1_b   = (const float*)d_in[12];
    const float* conv2_w   = (const float*)d_in[13];
    const float* conv2_b   = (const float*)d_in[14];

    float* out = (float*)d_out;
    float* fe = out;                             // 8*512*64 = 262144
    float* cw = out + Bn * T1n * En;             // 8*512*128 = 524288

    float* ws  = (float*)d_ws;
    float* xg  = ws;                             // 2*8*128*192 = 393216
    float* ctx = xg + 2 * Bn * T2n * Gn;         // 8*128*128  = 131072
    float* sC  = ctx + Bn * T2n * 128;           // 1024
    float* sL  = sC + Bn * T2n;                  // 4096
    float* Am  = sL + Bn * T1n;                  // 65536
    float* Bm  = Am + Bn * T2n * En;             // 65536
    float* Cm  = Bm + Bn * T2n * En;             // 65536

    k_xg  <<<Bn * T2n, 384, 0, stream>>>(char_seq, emb_table, Kf, bf, Kb, bb, xg);
    k_sL  <<<(Bn * T1n) / 4, 256, 0, stream>>>(lstm, w_char, sL);
    k_scan<<<16, 384, 0, stream>>>(xg, Rf, bf, Rb, bb, char_seq, ctx);
    k_ctxw<<<Bn * T2n, 128, 0, stream>>>(ctx, conv1_w, conv2_w, w_char, Am, Bm, Cm, sC);
    k_final<<<(Bn * T1n) / 8, 128, 0, stream>>>(sL, sC, w_char, b_char, conv1_b,
                                                conv2_w, conv2_b, Am, Bm, Cm, fe, cw);
}

// Round 3
// 184.237 us; speedup vs baseline: 1.1615x; 1.1615x over previous
//
#include <hip/hip_runtime.h>
#include <hip/hip_bf16.h>
#include <math.h>

// Shapes: B=8, T1=512, T2=128, LA=128, E=64, G=3E=192, DL=256
#define Bn 8
#define T1n 512
#define T2n 128
#define En 64
#define Gn 192
#define DLn 256

// LDS-only barrier: no vmcnt drain (keeps prefetched global loads + the
// fire-and-forget ctx stores in flight across the barrier).
__device__ __forceinline__ void bar_lds() {
    asm volatile("s_waitcnt lgkmcnt(0)\n\ts_barrier" ::: "memory");
}

__device__ __forceinline__ float fast_rcp(float x) { return __builtin_amdgcn_rcpf(x); }

// ---------------------------------------------------------------------------
// K1: xg[d][b][t][j] = b_d[0][j] + sum_e emb_table[char_seq[b][t]][e] * K_d[e][j]
// grid: B*T2 = 1024 blocks, 384 threads (2 dirs x 192 gates)
// ---------------------------------------------------------------------------
__global__ __launch_bounds__(384) void k_xg(const int* __restrict__ char_seq,
                                            const float* __restrict__ emb_table,
                                            const float* __restrict__ Kf,
                                            const float* __restrict__ bf,
                                            const float* __restrict__ Kb,
                                            const float* __restrict__ bb,
                                            float* __restrict__ xg) {
    int bt = blockIdx.x;              // 0..1023
    int b = bt >> 7, t = bt & 127;
    int tid = threadIdx.x;            // 0..383
    __shared__ __align__(16) float emb[En];
    if (tid < En) {
        int cs = char_seq[b * T2n + t];
        emb[tid] = emb_table[cs * En + tid];
    }
    __syncthreads();
    int d = tid / Gn;                 // wave-uniform (192 = 3 waves)
    int j = tid - d * Gn;
    const float* K = d ? Kb : Kf;
    const float* bias = d ? bb : bf;  // row 0
    float acc = bias[j];
    #pragma unroll
    for (int e = 0; e < En; ++e) acc = fmaf(emb[e], K[e * Gn + j], acc);
    xg[((d * Bn + b) * T2n + t) * Gn + j] = acc;
}

// ---------------------------------------------------------------------------
// K2: sL[b][t] = dot(lstm[b][t][:], w_char[0:256])
// ---------------------------------------------------------------------------
__global__ __launch_bounds__(256) void k_sL(const float* __restrict__ lstm,
                                            const float* __restrict__ w_char,
                                            float* __restrict__ sL) {
    int wave = threadIdx.x >> 6;
    int lane = threadIdx.x & 63;
    int bt = blockIdx.x * 4 + wave;   // 0..4095
    const float4* row = (const float4*)(lstm + (size_t)bt * DLn);
    const float4* wl  = (const float4*)(w_char);
    float4 r = row[lane];
    float4 w = wl[lane];
    float s = r.x * w.x + r.y * w.y + r.z * w.z + r.w * w.w;
    #pragma unroll
    for (int off = 32; off; off >>= 1) s += __shfl_down(s, off);
    if (lane == 0) sL[bt] = s;
}

// ---------------------------------------------------------------------------
// K3: sequential GRU scan, v3: 16 blocks = (b, dir), 256 threads = 4 waves.
// wave w owns u in [16w,16w+16); lane kq = lane>>6.. no: kq = lane>>4 owns
// k in [16kq,16kq+16). Per step: 48 FMAs/thread, in-register butterfly
// combine (shfl_xor 16/32), redundant gate compute in all kq groups, ONE
// ds_write+barrier+ds_read round trip per step. Fast sigmoid/tanh via
// v_exp + v_rcp (no libm tanh, no precise-div sequences on the chain).
// ---------------------------------------------------------------------------
__global__ __launch_bounds__(256) void k_scan(const float* __restrict__ xg,
                                              const float* __restrict__ Rf,
                                              const float* __restrict__ bf,
                                              const float* __restrict__ Rb,
                                              const float* __restrict__ bb,
                                              const int* __restrict__ char_seq,
                                              float* __restrict__ ctx) {
    int blk = blockIdx.x;             // 0..15
    int b = blk & 7, d = blk >> 3;
    int tid = threadIdx.x;            // 0..255
    int w = tid >> 6;                 // wave 0..3
    int lane = tid & 63;
    int ul = lane & 15;
    int u = (w << 4) | ul;            // 0..63 : this thread's hidden unit
    int kq = lane >> 4;               // 0..3  : this thread's k-slice
    int k0 = kq << 4;

    const float* R = d ? Rb : Rf;
    const float* b1 = (d ? bb : bf) + Gn;   // b[1]
    float Rcol[3][16];
    #pragma unroll
    for (int g = 0; g < 3; ++g)
        #pragma unroll
        for (int k = 0; k < 16; ++k)
            Rcol[g][k] = R[(k0 + k) * Gn + g * En + u];
    float bias3[3];
    #pragma unroll
    for (int g = 0; g < 3; ++g) bias3[g] = b1[g * En + u];

    __shared__ __align__(16) float h_lds[En];
    __shared__ int mloc[T2n];
    if (tid < En) h_lds[tid] = 0.f;
    if (tid < T2n) mloc[tid] = char_seq[b * T2n + tid];
    float hreg = 0.f, y = 0.f;

    const float* xgb = xg + (size_t)(d * Bn + b) * T2n * Gn;
    float* ctxb = ctx + (size_t)b * T2n * 128 + d * En;
    int i0 = d ? (T2n - 1) : 0;
    int istep = d ? -1 : 1;

    // xg prefetch pipeline, depth 2
    float x0[3], x1[3];
    #pragma unroll
    for (int g = 0; g < 3; ++g) x0[g] = xgb[i0 * Gn + g * En + u];
    #pragma unroll
    for (int g = 0; g < 3; ++g) x1[g] = xgb[(i0 + istep) * Gn + g * En + u];
    __syncthreads();

    for (int step = 0; step < T2n; ++step) {
        int idx = i0 + istep * step;
        // prefetch step+2
        float x2[3];
        {
            int sp = step + 2; if (sp > T2n - 1) sp = T2n - 1;
            int idxp = i0 + istep * sp;
            #pragma unroll
            for (int g = 0; g < 3; ++g) x2[g] = xgb[idxp * Gn + g * En + u];
        }
        // partial dot over this thread's 16 k's, 3 gate columns interleaved
        const float4* hp = (const float4*)(h_lds + k0);
        float4 hv0 = hp[0], hv1 = hp[1], hv2 = hp[2], hv3 = hp[3];
        float hk[16] = {hv0.x, hv0.y, hv0.z, hv0.w, hv1.x, hv1.y, hv1.z, hv1.w,
                        hv2.x, hv2.y, hv2.z, hv2.w, hv3.x, hv3.y, hv3.z, hv3.w};
        float acc0 = 0.f, acc1 = 0.f, acc2 = 0.f;
        #pragma unroll
        for (int k = 0; k < 16; ++k) {
            acc0 = fmaf(hk[k], Rcol[0][k], acc0);
            acc1 = fmaf(hk[k], Rcol[1][k], acc1);
            acc2 = fmaf(hk[k], Rcol[2][k], acc2);
        }
        // butterfly combine across kq groups (in-register, no barrier)
        acc0 += __shfl_xor(acc0, 16, 64);  acc0 += __shfl_xor(acc0, 32, 64);
        acc1 += __shfl_xor(acc1, 16, 64);  acc1 += __shfl_xor(acc1, 32, 64);
        acc2 += __shfl_xor(acc2, 16, 64);  acc2 += __shfl_xor(acc2, 32, 64);
        // gates (redundant in all kq groups; identical inputs -> identical)
        float rz = acc0 + bias3[0], rr = acc1 + bias3[1], rh = acc2 + bias3[2];
        float z = fast_rcp(1.f + __expf(-(x0[0] + rz)));
        float r = fast_rcp(1.f + __expf(-(x0[1] + rr)));
        float a = x0[2] + r * rh;
        float hh = 1.f - 2.f * fast_rcp(1.f + __expf(2.f * a));
        float hn = hh + z * (hreg - hh);
        if (mloc[idx] != 0) { hreg = hn; y = hn; }
        if (lane < 16) {
            h_lds[u] = hreg;
            ctxb[idx * 128 + u] = y;      // fire-and-forget global store
        }
        bar_lds();
        #pragma unroll
        for (int g = 0; g < 3; ++g) { x0[g] = x1[g]; x1[g] = x2[g]; }
    }
}

// ---------------------------------------------------------------------------
// K4: per (b,s): P0/P1 = ctx_row @ W1[tap], then
//   A  = P0@W20, Cm = P1@W21, Bm = P1@W20 + P0@W21, and sC = ctx_row . w_c
// ---------------------------------------------------------------------------
__global__ __launch_bounds__(128) void k_ctxw(const float* __restrict__ ctx,
                                              const float* __restrict__ conv1_w,
                                              const float* __restrict__ conv2_w,
                                              const float* __restrict__ w_char,
                                              float* __restrict__ Am,
                                              float* __restrict__ Bm,
                                              float* __restrict__ Cm,
                                              float* __restrict__ sC) {
    int bs = blockIdx.x;              // b*128+s
    int tid = threadIdx.x;            // 0..127
    __shared__ float crow[128];
    __shared__ float p0[En], p1[En];
    crow[tid] = ctx[(size_t)bs * 128 + tid];
    __syncthreads();
    if (tid < 64) {
        float s = crow[tid] * w_char[DLn + tid] + crow[64 + tid] * w_char[DLn + 64 + tid];
        #pragma unroll
        for (int off = 32; off; off >>= 1) s += __shfl_down(s, off);
        if (tid == 0) sC[bs] = s;
    }
    int tap = tid >> 6, o = tid & 63;
    const float* W = conv1_w + tap * 128 * En;
    float acc = 0.f;
    #pragma unroll
    for (int c = 0; c < 128; ++c) acc = fmaf(crow[c], W[c * En + o], acc);
    if (tap == 0) p0[o] = acc; else p1[o] = acc;
    __syncthreads();
    const float* W20 = conv2_w;            // [64][64]
    const float* W21 = conv2_w + En * En;
    if (tid < 64) {
        float a = 0.f, cm = 0.f;
        #pragma unroll
        for (int c = 0; c < En; ++c) {
            a  = fmaf(p0[c], W20[c * En + tid], a);
            cm = fmaf(p1[c], W21[c * En + tid], cm);
        }
        Am[(size_t)bs * En + tid] = a;
        Cm[(size_t)bs * En + tid] = cm;
    } else {
        int o2 = tid - 64;
        float bacc = 0.f;
        #pragma unroll
        for (int c = 0; c < En; ++c) {
            bacc = fmaf(p1[c], W20[c * En + o2], bacc);
            bacc = fmaf(p0[c], W21[c * En + o2], bacc);
        }
        Bm[(size_t)bs * En + o2] = bacc;
    }
}

// ---------------------------------------------------------------------------
// K5: per (b, 8-t tile): score rows -> char_weights; then
//   fe[b,t,o] = max_s ( sc[s]*A[s,o] + sc[s+1]*Bm[s+1,o] + sc[s+2]*Cm[s+2,o] + bb2[o] )
// ---------------------------------------------------------------------------
__global__ __launch_bounds__(128) void k_final(const float* __restrict__ sL,
                                               const float* __restrict__ sC,
                                               const float* __restrict__ w_char,
                                               const float* __restrict__ b_char,
                                               const float* __restrict__ conv1_b,
                                               const float* __restrict__ conv2_w,
                                               const float* __restrict__ conv2_b,
                                               const float* __restrict__ Am,
                                               const float* __restrict__ Bm,
                                               const float* __restrict__ Cm,
                                               float* __restrict__ fe,
                                               float* __restrict__ cw) {
    int blk = blockIdx.x;             // b(3b) x ttile(6b)
    int b = blk >> 6, ttile = blk & 63;
    int t0 = ttile * 8;
    int tid = threadIdx.x;            // 0..127
    float w_t = w_char[DLn + 128], w_i = w_char[DLn + 129], bc = b_char[0];
    __shared__ float sc8[8][T2n];
    {
        int s = tid;
        float sCs = sC[b * T2n + s] + w_i * (float)s + bc;
        #pragma unroll
        for (int tt = 0; tt < 8; ++tt) {
            int t = t0 + tt;
            float v = sL[b * T1n + t] + sCs + w_t * (float)t;
            sc8[tt][s] = v;
            cw[((size_t)(b * T1n + t)) * T2n + s] = v;
        }
    }
    int o = tid & 63, p = tid >> 6;
    float bb2 = conv2_b[o];
    #pragma unroll
    for (int c = 0; c < En; ++c)
        bb2 += conv1_b[c] * (conv2_w[c * En + o] + conv2_w[En * En + c * En + o]);
    __syncthreads();

    float acc[8];
    #pragma unroll
    for (int tt = 0; tt < 8; ++tt) acc[tt] = -__builtin_inff();
    const float* Ab = Am + (size_t)(b * T2n) * En + o;
    const float* Bb = Bm + (size_t)(b * T2n) * En + o;
    const float* Cb = Cm + (size_t)(b * T2n) * En + o;
    for (int s = p; s < T2n - 2; s += 2) {
        float a  = Ab[s * En];
        float bm = Bb[(s + 1) * En];
        float cm = Cb[(s + 2) * En];
        #pragma unroll
        for (int tt = 0; tt < 8; ++tt) {
            float v = fmaf(sc8[tt][s], a,
                      fmaf(sc8[tt][s + 1], bm,
                      fmaf(sc8[tt][s + 2], cm, bb2)));
            acc[tt] = fmaxf(acc[tt], v);
        }
    }
    __shared__ float red[64][9];
    if (p == 1) {
        #pragma unroll
        for (int tt = 0; tt < 8; ++tt) red[o][tt] = acc[tt];
    }
    __syncthreads();
    if (p == 0) {
        #pragma unroll
        for (int tt = 0; tt < 8; ++tt) {
            float v = fmaxf(acc[tt], red[o][tt]);
            fe[((size_t)(b * T1n + t0 + tt)) * En + o] = v;
        }
    }
}

// ---------------------------------------------------------------------------
extern "C" void kernel_launch(void* const* d_in, const int* in_sizes, int n_in,
                              void* d_out, int out_size, void* d_ws, size_t ws_size,
                              hipStream_t stream) {
    const float* lstm      = (const float*)d_in[0];
    const int*   char_seq  = (const int*)d_in[1];
    const float* emb_table = (const float*)d_in[2];
    const float* Kf        = (const float*)d_in[3];
    const float* Rf        = (const float*)d_in[4];
    const float* bf        = (const float*)d_in[5];
    const float* Kb        = (const float*)d_in[6];
    const float* Rb        = (const float*)d_in[7];
    const float* bb        = (const float*)d_in[8];
    const float* w_char    = (const float*)d_in[9];
    const float* b_char    = (const float*)d_in[10];
    const float* conv1_w   = (const float*)d_in[11];
    const float* conv1_b   = (const float*)d_in[12];
    const float* conv2_w   = (const float*)d_in[13];
    const float* conv2_b   = (const float*)d_in[14];

    float* out = (float*)d_out;
    float* fe = out;                             // 8*512*64 = 262144
    float* cw = out + Bn * T1n * En;             // 8*512*128 = 524288

    float* ws  = (float*)d_ws;
    float* xg  = ws;                             // 2*8*128*192 = 393216
    float* ctx = xg + 2 * Bn * T2n * Gn;         // 8*128*128  = 131072
    float* sC  = ctx + Bn * T2n * 128;           // 1024
    float* sL  = sC + Bn * T2n;                  // 4096
    float* Am  = sL + Bn * T1n;                  // 65536
    float* Bm  = Am + Bn * T2n * En;             // 65536
    float* Cm  = Bm + Bn * T2n * En;             // 65536

    k_xg  <<<Bn * T2n, 384, 0, stream>>>(char_seq, emb_table, Kf, bf, Kb, bb, xg);
    k_sL  <<<(Bn * T1n) / 4, 256, 0, stream>>>(lstm, w_char, sL);
    k_scan<<<16, 256, 0, stream>>>(xg, Rf, bf, Rb, bb, char_seq, ctx);
    k_ctxw<<<Bn * T2n, 128, 0, stream>>>(ctx, conv1_w, conv2_w, w_char, Am, Bm, Cm, sC);
    k_final<<<(Bn * T1n) / 8, 128, 0, stream>>>(sL, sC, w_char, b_char, conv1_b,
                                                conv2_w, conv2_b, Am, Bm, Cm, fe, cw);
}

// Round 4
// 179.257 us; speedup vs baseline: 1.1938x; 1.0278x over previous
//
#include <hip/hip_runtime.h>
#include <hip/hip_bf16.h>
#include <math.h>

// Shapes: B=8, T1=512, T2=128, LA=128, E=64, G=3E=192, DL=256
#define Bn 8
#define T1n 512
#define T2n 128
#define En 64
#define Gn 192
#define DLn 256

// LDS-only barrier: no vmcnt drain (keeps prefetched global loads + the
// fire-and-forget ctx stores in flight across the barrier).
__device__ __forceinline__ void bar_lds() {
    asm volatile("s_waitcnt lgkmcnt(0)\n\ts_barrier" ::: "memory");
}

__device__ __forceinline__ float fast_rcp(float x) { return __builtin_amdgcn_rcpf(x); }

// Butterfly sums via gfx950 VALU cross-lane swaps (NOT the DS pipe --
// __shfl_xor compiles to ds_swizzle/ds_bpermute at ~120 cyc; these are ~4).
// With y = x, permlaneN_swap leaves {lo,lo} in one reg and {hi,hi} in the
// other (either pairing), so x'+y' = the xor-N sum in every lane.
typedef unsigned int uint2v __attribute__((ext_vector_type(2)));

__device__ __forceinline__ float xor16_sum(float v) {
#if __has_builtin(__builtin_amdgcn_permlane16_swap)
    uint2v r = __builtin_amdgcn_permlane16_swap(__builtin_bit_cast(unsigned int, v),
                                                __builtin_bit_cast(unsigned int, v),
                                                false, false);
    return __builtin_bit_cast(float, r.x) + __builtin_bit_cast(float, r.y);
#else
    float x = v, y = v;
    asm volatile("v_permlane16_swap_b32 %0, %1" : "+v"(x), "+v"(y));
    return x + y;
#endif
}

__device__ __forceinline__ float xor32_sum(float v) {
#if __has_builtin(__builtin_amdgcn_permlane32_swap)
    uint2v r = __builtin_amdgcn_permlane32_swap(__builtin_bit_cast(unsigned int, v),
                                                __builtin_bit_cast(unsigned int, v),
                                                false, false);
    return __builtin_bit_cast(float, r.x) + __builtin_bit_cast(float, r.y);
#else
    float x = v, y = v;
    asm volatile("v_permlane32_swap_b32 %0, %1" : "+v"(x), "+v"(y));
    return x + y;
#endif
}

// ---------------------------------------------------------------------------
// K1: xg[d][b][t][j] = b_d[0][j] + sum_e emb_table[char_seq[b][t]][e] * K_d[e][j]
// ---------------------------------------------------------------------------
__global__ __launch_bounds__(384) void k_xg(const int* __restrict__ char_seq,
                                            const float* __restrict__ emb_table,
                                            const float* __restrict__ Kf,
                                            const float* __restrict__ bf,
                                            const float* __restrict__ Kb,
                                            const float* __restrict__ bb,
                                            float* __restrict__ xg) {
    int bt = blockIdx.x;              // 0..1023
    int b = bt >> 7, t = bt & 127;
    int tid = threadIdx.x;            // 0..383
    __shared__ __align__(16) float emb[En];
    if (tid < En) {
        int cs = char_seq[b * T2n + t];
        emb[tid] = emb_table[cs * En + tid];
    }
    __syncthreads();
    int d = tid / Gn;                 // wave-uniform (192 = 3 waves)
    int j = tid - d * Gn;
    const float* K = d ? Kb : Kf;
    const float* bias = d ? bb : bf;  // row 0
    float acc = bias[j];
    #pragma unroll
    for (int e = 0; e < En; ++e) acc = fmaf(emb[e], K[e * Gn + j], acc);
    xg[((d * Bn + b) * T2n + t) * Gn + j] = acc;
}

// ---------------------------------------------------------------------------
// K2: sL[b][t] = dot(lstm[b][t][:], w_char[0:256])
// ---------------------------------------------------------------------------
__global__ __launch_bounds__(256) void k_sL(const float* __restrict__ lstm,
                                            const float* __restrict__ w_char,
                                            float* __restrict__ sL) {
    int wave = threadIdx.x >> 6;
    int lane = threadIdx.x & 63;
    int bt = blockIdx.x * 4 + wave;   // 0..4095
    const float4* row = (const float4*)(lstm + (size_t)bt * DLn);
    const float4* wl  = (const float4*)(w_char);
    float4 r = row[lane];
    float4 w = wl[lane];
    float s = r.x * w.x + r.y * w.y + r.z * w.z + r.w * w.w;
    #pragma unroll
    for (int off = 32; off; off >>= 1) s += __shfl_down(s, off);
    if (lane == 0) sL[bt] = s;
}

// ---------------------------------------------------------------------------
// K3: sequential GRU scan, v4: 16 blocks = (b, dir), 256 threads = 4 waves.
// wave w owns u in [16w,16w+16); lane kq = lane>>4 owns k in [16kq,16kq+16).
// Per step: 48 FMAs/thread, VALU permlane butterfly combine (no DS pipe),
// redundant gate compute in all kq groups, mask bits in SGPR ballots (no LDS
// read on the chain), ONE ds_write+barrier+ds_read round trip per step.
// ---------------------------------------------------------------------------
__global__ __launch_bounds__(256) void k_scan(const float* __restrict__ xg,
                                              const float* __restrict__ Rf,
                                              const float* __restrict__ bf,
                                              const float* __restrict__ Rb,
                                              const float* __restrict__ bb,
                                              const int* __restrict__ char_seq,
                                              float* __restrict__ ctx) {
    int blk = blockIdx.x;             // 0..15
    int b = blk & 7, d = blk >> 3;
    int tid = threadIdx.x;            // 0..255
    int w = tid >> 6;                 // wave 0..3
    int lane = tid & 63;
    int ul = lane & 15;
    int u = (w << 4) | ul;            // 0..63 : this thread's hidden unit
    int kq = lane >> 4;               // 0..3  : this thread's k-slice
    int k0 = kq << 4;

    // mask bits: one ballot per 64 chars; wave-uniform scalar bit tests later
    unsigned long long mlo = __ballot(char_seq[b * T2n + lane] != 0);
    unsigned long long mhi = __ballot(char_seq[b * T2n + 64 + lane] != 0);

    const float* R = d ? Rb : Rf;
    const float* b1 = (d ? bb : bf) + Gn;   // b[1]
    float Rcol[3][16];
    #pragma unroll
    for (int g = 0; g < 3; ++g)
        #pragma unroll
        for (int k = 0; k < 16; ++k)
            Rcol[g][k] = R[(k0 + k) * Gn + g * En + u];
    float bias3[3];
    #pragma unroll
    for (int g = 0; g < 3; ++g) bias3[g] = b1[g * En + u];

    __shared__ __align__(16) float h_lds[En];
    if (tid < En) h_lds[tid] = 0.f;
    float hreg = 0.f, y = 0.f;

    const float* xgb = xg + (size_t)(d * Bn + b) * T2n * Gn;
    float* ctxb = ctx + (size_t)b * T2n * 128 + d * En;
    int i0 = d ? (T2n - 1) : 0;
    int istep = d ? -1 : 1;

    // xg prefetch pipeline, depth 2
    float x0[3], x1[3];
    #pragma unroll
    for (int g = 0; g < 3; ++g) x0[g] = xgb[i0 * Gn + g * En + u];
    #pragma unroll
    for (int g = 0; g < 3; ++g) x1[g] = xgb[(i0 + istep) * Gn + g * En + u];
    bar_lds();

    for (int step = 0; step < T2n; ++step) {
        int idx = i0 + istep * step;
        // prefetch step+2
        float x2[3];
        {
            int sp = step + 2; if (sp > T2n - 1) sp = T2n - 1;
            int idxp = i0 + istep * sp;
            #pragma unroll
            for (int g = 0; g < 3; ++g) x2[g] = xgb[idxp * Gn + g * En + u];
        }
        // partial dot over this thread's 16 k's, 3 gate columns interleaved
        const float4* hp = (const float4*)(h_lds + k0);
        float4 hv0 = hp[0], hv1 = hp[1], hv2 = hp[2], hv3 = hp[3];
        float hk[16] = {hv0.x, hv0.y, hv0.z, hv0.w, hv1.x, hv1.y, hv1.z, hv1.w,
                        hv2.x, hv2.y, hv2.z, hv2.w, hv3.x, hv3.y, hv3.z, hv3.w};
        float acc0 = 0.f, acc1 = 0.f, acc2 = 0.f;
        #pragma unroll
        for (int k = 0; k < 16; ++k) {
            acc0 = fmaf(hk[k], Rcol[0][k], acc0);
            acc1 = fmaf(hk[k], Rcol[1][k], acc1);
            acc2 = fmaf(hk[k], Rcol[2][k], acc2);
        }
        // VALU butterfly combine across kq groups (all lanes get full sums)
        acc0 = xor32_sum(xor16_sum(acc0));
        acc1 = xor32_sum(xor16_sum(acc1));
        acc2 = xor32_sum(xor16_sum(acc2));
        // gates (redundant in all kq groups; identical inputs -> identical)
        float rz = acc0 + bias3[0], rr = acc1 + bias3[1], rh = acc2 + bias3[2];
        float z = fast_rcp(1.f + __expf(-(x0[0] + rz)));
        float r = fast_rcp(1.f + __expf(-(x0[1] + rr)));
        float a = x0[2] + r * rh;
        float hh = 1.f - 2.f * fast_rcp(1.f + __expf(2.f * a));
        float hn = hh + z * (hreg - hh);
        bool m = (idx < 64) ? ((mlo >> idx) & 1ull) : ((mhi >> (idx - 64)) & 1ull);
        if (m) { hreg = hn; y = hn; }
        if (lane < 16) {
            h_lds[u] = hreg;
            ctxb[idx * 128 + u] = y;      // fire-and-forget global store
        }
        bar_lds();
        #pragma unroll
        for (int g = 0; g < 3; ++g) { x0[g] = x1[g]; x1[g] = x2[g]; }
    }
}

// ---------------------------------------------------------------------------
// K4: per (b,s): P0/P1 = ctx_row @ W1[tap], then
//   A  = P0@W20, Cm = P1@W21, Bm = P1@W20 + P0@W21, and sC = ctx_row . w_c
// ---------------------------------------------------------------------------
__global__ __launch_bounds__(128) void k_ctxw(const float* __restrict__ ctx,
                                              const float* __restrict__ conv1_w,
                                              const float* __restrict__ conv2_w,
                                              const float* __restrict__ w_char,
                                              float* __restrict__ Am,
                                              float* __restrict__ Bm,
                                              float* __restrict__ Cm,
                                              float* __restrict__ sC) {
    int bs = blockIdx.x;              // b*128+s
    int tid = threadIdx.x;            // 0..127
    __shared__ float crow[128];
    __shared__ float p0[En], p1[En];
    crow[tid] = ctx[(size_t)bs * 128 + tid];
    __syncthreads();
    if (tid < 64) {
        float s = crow[tid] * w_char[DLn + tid] + crow[64 + tid] * w_char[DLn + 64 + tid];
        #pragma unroll
        for (int off = 32; off; off >>= 1) s += __shfl_down(s, off);
        if (tid == 0) sC[bs] = s;
    }
    int tap = tid >> 6, o = tid & 63;
    const float* W = conv1_w + tap * 128 * En;
    float acc = 0.f;
    #pragma unroll
    for (int c = 0; c < 128; ++c) acc = fmaf(crow[c], W[c * En + o], acc);
    if (tap == 0) p0[o] = acc; else p1[o] = acc;
    __syncthreads();
    const float* W20 = conv2_w;            // [64][64]
    const float* W21 = conv2_w + En * En;
    if (tid < 64) {
        float a = 0.f, cm = 0.f;
        #pragma unroll
        for (int c = 0; c < En; ++c) {
            a  = fmaf(p0[c], W20[c * En + tid], a);
            cm = fmaf(p1[c], W21[c * En + tid], cm);
        }
        Am[(size_t)bs * En + tid] = a;
        Cm[(size_t)bs * En + tid] = cm;
    } else {
        int o2 = tid - 64;
        float bacc = 0.f;
        #pragma unroll
        for (int c = 0; c < En; ++c) {
            bacc = fmaf(p1[c], W20[c * En + o2], bacc);
            bacc = fmaf(p0[c], W21[c * En + o2], bacc);
        }
        Bm[(size_t)bs * En + o2] = bacc;
    }
}

// ---------------------------------------------------------------------------
// K5: per (b, 8-t tile): score rows -> char_weights; then
//   fe[b,t,o] = max_s ( sc[s]*A[s,o] + sc[s+1]*Bm[s+1,o] + sc[s+2]*Cm[s+2,o] + bb2[o] )
// ---------------------------------------------------------------------------
__global__ __launch_bounds__(128) void k_final(const float* __restrict__ sL,
                                               const float* __restrict__ sC,
                                               const float* __restrict__ w_char,
                                               const float* __restrict__ b_char,
                                               const float* __restrict__ conv1_b,
                                               const float* __restrict__ conv2_w,
                                               const float* __restrict__ conv2_b,
                                               const float* __restrict__ Am,
                                               const float* __restrict__ Bm,
                                               const float* __restrict__ Cm,
                                               float* __restrict__ fe,
                                               float* __restrict__ cw) {
    int blk = blockIdx.x;             // b(3b) x ttile(6b)
    int b = blk >> 6, ttile = blk & 63;
    int t0 = ttile * 8;
    int tid = threadIdx.x;            // 0..127
    float w_t = w_char[DLn + 128], w_i = w_char[DLn + 129], bc = b_char[0];
    __shared__ float sc8[8][T2n];
    {
        int s = tid;
        float sCs = sC[b * T2n + s] + w_i * (float)s + bc;
        #pragma unroll
        for (int tt = 0; tt < 8; ++tt) {
            int t = t0 + tt;
            float v = sL[b * T1n + t] + sCs + w_t * (float)t;
            sc8[tt][s] = v;
            cw[((size_t)(b * T1n + t)) * T2n + s] = v;
        }
    }
    int o = tid & 63, p = tid >> 6;
    float bb2 = conv2_b[o];
    #pragma unroll
    for (int c = 0; c < En; ++c)
        bb2 += conv1_b[c] * (conv2_w[c * En + o] + conv2_w[En * En + c * En + o]);
    __syncthreads();

    float acc[8];
    #pragma unroll
    for (int tt = 0; tt < 8; ++tt) acc[tt] = -__builtin_inff();
    const float* Ab = Am + (size_t)(b * T2n) * En + o;
    const float* Bb = Bm + (size_t)(b * T2n) * En + o;
    const float* Cb = Cm + (size_t)(b * T2n) * En + o;
    for (int s = p; s < T2n - 2; s += 2) {
        float a  = Ab[s * En];
        float bm = Bb[(s + 1) * En];
        float cm = Cb[(s + 2) * En];
        #pragma unroll
        for (int tt = 0; tt < 8; ++tt) {
            float v = fmaf(sc8[tt][s], a,
                      fmaf(sc8[tt][s + 1], bm,
                      fmaf(sc8[tt][s + 2], cm, bb2)));
            acc[tt] = fmaxf(acc[tt], v);
        }
    }
    __shared__ float red[64][9];
    if (p == 1) {
        #pragma unroll
        for (int tt = 0; tt < 8; ++tt) red[o][tt] = acc[tt];
    }
    __syncthreads();
    if (p == 0) {
        #pragma unroll
        for (int tt = 0; tt < 8; ++tt) {
            float v = fmaxf(acc[tt], red[o][tt]);
            fe[((size_t)(b * T1n + t0 + tt)) * En + o] = v;
        }
    }
}

// ---------------------------------------------------------------------------
extern "C" void kernel_launch(void* const* d_in, const int* in_sizes, int n_in,
                              void* d_out, int out_size, void* d_ws, size_t ws_size,
                              hipStream_t stream) {
    const float* lstm      = (const float*)d_in[0];
    const int*   char_seq  = (const int*)d_in[1];
    const float* emb_table = (const float*)d_in[2];
    const float* Kf        = (const float*)d_in[3];
    const float* Rf        = (const float*)d_in[4];
    const float* bf        = (const float*)d_in[5];
    const float* Kb        = (const float*)d_in[6];
    const float* Rb        = (const float*)d_in[7];
    const float* bb        = (const float*)d_in[8];
    const float* w_char    = (const float*)d_in[9];
    const float* b_char    = (const float*)d_in[10];
    const float* conv1_w   = (const float*)d_in[11];
    const float* conv1_b   = (const float*)d_in[12];
    const float* conv2_w   = (const float*)d_in[13];
    const float* conv2_b   = (const float*)d_in[14];

    float* out = (float*)d_out;
    float* fe = out;                             // 8*512*64 = 262144
    float* cw = out + Bn * T1n * En;             // 8*512*128 = 524288

    float* ws  = (float*)d_ws;
    float* xg  = ws;                             // 2*8*128*192 = 393216
    float* ctx = xg + 2 * Bn * T2n * Gn;         // 8*128*128  = 131072
    float* sC  = ctx + Bn * T2n * 128;           // 1024
    float* sL  = sC + Bn * T2n;                  // 4096
    float* Am  = sL + Bn * T1n;                  // 65536
    float* Bm  = Am + Bn * T2n * En;             // 65536
    float* Cm  = Bm + Bn * T2n * En;             // 65536

    k_xg  <<<Bn * T2n, 384, 0, stream>>>(char_seq, emb_table, Kf, bf, Kb, bb, xg);
    k_sL  <<<(Bn * T1n) / 4, 256, 0, stream>>>(lstm, w_char, sL);
    k_scan<<<16, 256, 0, stream>>>(xg, Rf, bf, Rb, bb, char_seq, ctx);
    k_ctxw<<<Bn * T2n, 128, 0, stream>>>(ctx, conv1_w, conv2_w, w_char, Am, Bm, Cm, sC);
    k_final<<<(Bn * T1n) / 8, 128, 0, stream>>>(sL, sC, w_char, b_char, conv1_b,
                                                conv2_w, conv2_b, Am, Bm, Cm, fe, cw);
}

// Round 5
// 171.996 us; speedup vs baseline: 1.2442x; 1.0422x over previous
//
#include <hip/hip_runtime.h>
#include <hip/hip_bf16.h>
#include <math.h>

// Shapes: B=8, T1=512, T2=128, LA=128, E=64, G=3E=192, DL=256
#define Bn 8
#define T1n 512
#define T2n 128
#define En 64
#define Gn 192
#define DLn 256

typedef __attribute__((ext_vector_type(8))) short short8;
typedef __attribute__((ext_vector_type(4))) float float4v;

__device__ __forceinline__ float fast_rcp(float x) { return __builtin_amdgcn_rcpf(x); }

// round-to-nearest-even f32 -> bf16 bits
__device__ __forceinline__ unsigned short f32_to_bf16(float v) {
    unsigned u = __builtin_bit_cast(unsigned, v);
    u += 0x7FFFu + ((u >> 16) & 1u);
    return (unsigned short)(u >> 16);
}

// ---------------------------------------------------------------------------
// K1 (fused): blocks 0..1023: xg = emb.K + b[0] for both dirs.
//             blocks 1024.. : sL[b][t] = dot(lstm[b][t], w_char[0:256]).
// ---------------------------------------------------------------------------
__global__ __launch_bounds__(384) void k_pre(const int* __restrict__ char_seq,
                                             const float* __restrict__ emb_table,
                                             const float* __restrict__ Kf,
                                             const float* __restrict__ bf,
                                             const float* __restrict__ Kb,
                                             const float* __restrict__ bb,
                                             const float* __restrict__ lstm,
                                             const float* __restrict__ w_char,
                                             float* __restrict__ xg,
                                             float* __restrict__ sL) {
    int tid = threadIdx.x;            // 0..383
    if (blockIdx.x < 1024) {
        int bt = blockIdx.x;          // 0..1023
        int b = bt >> 7, t = bt & 127;
        __shared__ __align__(16) float emb[En];
        if (tid < En) {
            int cs = char_seq[b * T2n + t];
            emb[tid] = emb_table[cs * En + tid];
        }
        __syncthreads();
        int d = tid / Gn;             // wave-uniform
        int j = tid - d * Gn;
        const float* K = d ? Kb : Kf;
        const float* bias = d ? bb : bf;
        float acc = bias[j];
        #pragma unroll
        for (int e = 0; e < En; ++e) acc = fmaf(emb[e], K[e * Gn + j], acc);
        xg[((d * Bn + b) * T2n + t) * Gn + j] = acc;
    } else {
        int wave = tid >> 6, lane = tid & 63;
        int bt = (blockIdx.x - 1024) * 6 + wave;
        if (bt < Bn * T1n) {
            const float4* row = (const float4*)(lstm + (size_t)bt * DLn);
            const float4* wl  = (const float4*)(w_char);
            float4 r = row[lane];
            float4 w = wl[lane];
            float s = r.x * w.x + r.y * w.y + r.z * w.z + r.w * w.w;
            #pragma unroll
            for (int off = 32; off; off >>= 1) s += __shfl_down(s, off);
            if (lane == 0) sL[bt] = s;
        }
    }
}

// ---------------------------------------------------------------------------
// K3: sequential GRU scan, v5: 16 blocks = (b, dir), ONE wave (64 threads).
// Lane l holds h[l] in f32. Per step, h.R (1x64 @ 64x192) is computed by
// MFMA 16x16x32 bf16 with A = h replicated over 16 rows:
//   A-frag: lane supplies A[m=lane&15][k=quad*8+j] -> all lanes of a quad
//   read the SAME 16B of the 128B LDS h-buffer (broadcast, conflict-free).
//   B-frags (R tiles, bf16) preloaded once: 12 n-tiles x 2 k-tiles.
//   D: col=lane&15 (m89-verified) -> lane selects tile nt=quad via cndmask.
// No barrier, no cross-wave traffic, no race: single-wave LDS ordering is
// enforced by the compiler's lgkmcnt. State h stays f32 (only the MFMA
// multiplicand is bf16-rounded).
// ---------------------------------------------------------------------------
__global__ __launch_bounds__(64) void k_scan(const float* __restrict__ xg,
                                             const float* __restrict__ Rf,
                                             const float* __restrict__ bf,
                                             const float* __restrict__ Rb,
                                             const float* __restrict__ bb,
                                             const int* __restrict__ char_seq,
                                             float* __restrict__ ctx) {
    int blk = blockIdx.x;             // 0..15
    int b = blk & 7, d = blk >> 3;
    int lane = threadIdx.x;           // 0..63
    int quad = lane >> 4, col = lane & 15;

    // mask bits in SGPRs
    unsigned long long mlo = __ballot(char_seq[b * T2n + lane] != 0);
    unsigned long long mhi = __ballot(char_seq[b * T2n + 64 + lane] != 0);

    const float* R = d ? Rb : Rf;
    const float* b1 = (d ? bb : bf) + Gn;   // b[1]

    // preload B fragments (R in bf16): B[k][n], n=lane&15, k=quad*8+j
    short8 Bfrag[12][2];
    #pragma unroll
    for (int nt = 0; nt < 12; ++nt)
        #pragma unroll
        for (int kt = 0; kt < 2; ++kt) {
            short8 f;
            #pragma unroll
            for (int j = 0; j < 8; ++j) {
                float v = R[(kt * 32 + quad * 8 + j) * Gn + nt * 16 + col];
                f[j] = (short)f32_to_bf16(v);
            }
            Bfrag[nt][kt] = f;
        }
    float bz = b1[lane], br = b1[En + lane], bh = b1[2 * En + lane];

    __shared__ __align__(16) unsigned short hb[En];   // h in bf16, 128 B
    hb[lane] = 0;
    float hreg = 0.f, y = 0.f;

    const float* xgb = xg + (size_t)(d * Bn + b) * T2n * Gn;
    float* ctxb = ctx + (size_t)b * T2n * 128 + d * En;
    int i0 = d ? (T2n - 1) : 0;
    int istep = d ? -1 : 1;

    // xg prefetch pipeline, depth 3
    float x0[3], x1[3], x2[3];
    #pragma unroll
    for (int g = 0; g < 3; ++g) x0[g] = xgb[i0 * Gn + g * En + lane];
    #pragma unroll
    for (int g = 0; g < 3; ++g) x1[g] = xgb[(i0 + istep) * Gn + g * En + lane];
    #pragma unroll
    for (int g = 0; g < 3; ++g) x2[g] = xgb[(i0 + 2 * istep) * Gn + g * En + lane];

    bool q1 = (quad & 1) != 0, q2 = (quad & 2) != 0;
    const short8* ap = (const short8*)hb;

    for (int step = 0; step < T2n; ++step) {
        int idx = i0 + istep * step;
        // prefetch step+3
        float x3[3];
        {
            int sp = step + 3; if (sp > T2n - 1) sp = T2n - 1;
            int idxp = i0 + istep * sp;
            #pragma unroll
            for (int g = 0; g < 3; ++g) x3[g] = xgb[idxp * Gn + g * En + lane];
        }
        // A fragments: k-tile 0 = shorts [0..32), k-tile 1 = [32..64)
        short8 a0 = ap[quad];
        short8 a1 = ap[4 + quad];
        // 12 n-tiles, chained K accumulate
        float4v acc[12];
        #pragma unroll
        for (int nt = 0; nt < 12; ++nt) {
            float4v z4 = {0.f, 0.f, 0.f, 0.f};
            z4 = __builtin_amdgcn_mfma_f32_16x16x32_bf16(a1, Bfrag[nt][1], z4, 0, 0, 0);
            acc[nt] = __builtin_amdgcn_mfma_f32_16x16x32_bf16(a0, Bfrag[nt][0], z4, 0, 0, 0);
        }
        // select this lane's rz/rr/rh (tile nt = quad, col = lane&15)
        float z01 = q1 ? acc[1].x : acc[0].x;
        float z23 = q1 ? acc[3].x : acc[2].x;
        float rz  = (q2 ? z23 : z01) + bz;
        float r01 = q1 ? acc[5].x : acc[4].x;
        float r23 = q1 ? acc[7].x : acc[6].x;
        float rr  = (q2 ? r23 : r01) + br;
        float h01 = q1 ? acc[9].x : acc[8].x;
        float h23 = q1 ? acc[11].x : acc[10].x;
        float rh  = (q2 ? h23 : h01) + bh;
        // gates
        float z = fast_rcp(1.f + __expf(-(x0[0] + rz)));
        float r = fast_rcp(1.f + __expf(-(x0[1] + rr)));
        float a = x0[2] + r * rh;
        float hh = 1.f - 2.f * fast_rcp(1.f + __expf(2.f * a));
        float hn = hh + z * (hreg - hh);
        bool m = (idx < 64) ? ((mlo >> idx) & 1ull) : ((mhi >> (idx - 64)) & 1ull);
        if (m) { hreg = hn; y = hn; }
        ctxb[idx * 128 + lane] = y;       // fire-and-forget global store
        hb[lane] = f32_to_bf16(hreg);     // same-wave LDS; lgkmcnt-ordered
        #pragma unroll
        for (int g = 0; g < 3; ++g) { x0[g] = x1[g]; x1[g] = x2[g]; x2[g] = x3[g]; }
    }
}

// ---------------------------------------------------------------------------
// K4: per (b,s): P0/P1 = ctx_row @ W1[tap], then
//   A  = P0@W20, Cm = P1@W21, Bm = P1@W20 + P0@W21, and sC = ctx_row . w_c
// ---------------------------------------------------------------------------
__global__ __launch_bounds__(128) void k_ctxw(const float* __restrict__ ctx,
                                              const float* __restrict__ conv1_w,
                                              const float* __restrict__ conv2_w,
                                              const float* __restrict__ w_char,
                                              float* __restrict__ Am,
                                              float* __restrict__ Bm,
                                              float* __restrict__ Cm,
                                              float* __restrict__ sC) {
    int bs = blockIdx.x;              // b*128+s
    int tid = threadIdx.x;            // 0..127
    __shared__ float crow[128];
    __shared__ float p0[En], p1[En];
    crow[tid] = ctx[(size_t)bs * 128 + tid];
    __syncthreads();
    if (tid < 64) {
        float s = crow[tid] * w_char[DLn + tid] + crow[64 + tid] * w_char[DLn + 64 + tid];
        #pragma unroll
        for (int off = 32; off; off >>= 1) s += __shfl_down(s, off);
        if (tid == 0) sC[bs] = s;
    }
    int tap = tid >> 6, o = tid & 63;
    const float* W = conv1_w + tap * 128 * En;
    float acc = 0.f;
    #pragma unroll
    for (int c = 0; c < 128; ++c) acc = fmaf(crow[c], W[c * En + o], acc);
    if (tap == 0) p0[o] = acc; else p1[o] = acc;
    __syncthreads();
    const float* W20 = conv2_w;            // [64][64]
    const float* W21 = conv2_w + En * En;
    if (tid < 64) {
        float a = 0.f, cm = 0.f;
        #pragma unroll
        for (int c = 0; c < En; ++c) {
            a  = fmaf(p0[c], W20[c * En + tid], a);
            cm = fmaf(p1[c], W21[c * En + tid], cm);
        }
        Am[(size_t)bs * En + tid] = a;
        Cm[(size_t)bs * En + tid] = cm;
    } else {
        int o2 = tid - 64;
        float bacc = 0.f;
        #pragma unroll
        for (int c = 0; c < En; ++c) {
            bacc = fmaf(p1[c], W20[c * En + o2], bacc);
            bacc = fmaf(p0[c], W21[c * En + o2], bacc);
        }
        Bm[(size_t)bs * En + o2] = bacc;
    }
}

// ---------------------------------------------------------------------------
// K5: per (b, 8-t tile): score rows -> char_weights; then
//   fe[b,t,o] = max_s ( sc[s]*A[s,o] + sc[s+1]*Bm[s+1,o] + sc[s+2]*Cm[s+2,o] + bb2[o] )
// ---------------------------------------------------------------------------
__global__ __launch_bounds__(128) void k_final(const float* __restrict__ sL,
                                               const float* __restrict__ sC,
                                               const float* __restrict__ w_char,
                                               const float* __restrict__ b_char,
                                               const float* __restrict__ conv1_b,
                                               const float* __restrict__ conv2_w,
                                               const float* __restrict__ conv2_b,
                                               const float* __restrict__ Am,
                                               const float* __restrict__ Bm,
                                               const float* __restrict__ Cm,
                                               float* __restrict__ fe,
                                               float* __restrict__ cw) {
    int blk = blockIdx.x;             // b(3b) x ttile(6b)
    int b = blk >> 6, ttile = blk & 63;
    int t0 = ttile * 8;
    int tid = threadIdx.x;            // 0..127
    float w_t = w_char[DLn + 128], w_i = w_char[DLn + 129], bc = b_char[0];
    __shared__ float sc8[8][T2n];
    {
        int s = tid;
        float sCs = sC[b * T2n + s] + w_i * (float)s + bc;
        #pragma unroll
        for (int tt = 0; tt < 8; ++tt) {
            int t = t0 + tt;
            float v = sL[b * T1n + t] + sCs + w_t * (float)t;
            sc8[tt][s] = v;
            cw[((size_t)(b * T1n + t)) * T2n + s] = v;
        }
    }
    int o = tid & 63, p = tid >> 6;
    float bb2 = conv2_b[o];
    #pragma unroll
    for (int c = 0; c < En; ++c)
        bb2 += conv1_b[c] * (conv2_w[c * En + o] + conv2_w[En * En + c * En + o]);
    __syncthreads();

    float acc[8];
    #pragma unroll
    for (int tt = 0; tt < 8; ++tt) acc[tt] = -__builtin_inff();
    const float* Ab = Am + (size_t)(b * T2n) * En + o;
    const float* Bb = Bm + (size_t)(b * T2n) * En + o;
    const float* Cb = Cm + (size_t)(b * T2n) * En + o;
    for (int s = p; s < T2n - 2; s += 2) {
        float a  = Ab[s * En];
        float bm = Bb[(s + 1) * En];
        float cm = Cb[(s + 2) * En];
        #pragma unroll
        for (int tt = 0; tt < 8; ++tt) {
            float v = fmaf(sc8[tt][s], a,
                      fmaf(sc8[tt][s + 1], bm,
                      fmaf(sc8[tt][s + 2], cm, bb2)));
            acc[tt] = fmaxf(acc[tt], v);
        }
    }
    __shared__ float red[64][9];
    if (p == 1) {
        #pragma unroll
        for (int tt = 0; tt < 8; ++tt) red[o][tt] = acc[tt];
    }
    __syncthreads();
    if (p == 0) {
        #pragma unroll
        for (int tt = 0; tt < 8; ++tt) {
            float v = fmaxf(acc[tt], red[o][tt]);
            fe[((size_t)(b * T1n + t0 + tt)) * En + o] = v;
        }
    }
}

// ---------------------------------------------------------------------------
extern "C" void kernel_launch(void* const* d_in, const int* in_sizes, int n_in,
                              void* d_out, int out_size, void* d_ws, size_t ws_size,
                              hipStream_t stream) {
    const float* lstm      = (const float*)d_in[0];
    const int*   char_seq  = (const int*)d_in[1];
    const float* emb_table = (const float*)d_in[2];
    const float* Kf        = (const float*)d_in[3];
    const float* Rf        = (const float*)d_in[4];
    const float* bf        = (const float*)d_in[5];
    const float* Kb        = (const float*)d_in[6];
    const float* Rb        = (const float*)d_in[7];
    const float* bb        = (const float*)d_in[8];
    const float* w_char    = (const float*)d_in[9];
    const float* b_char    = (const float*)d_in[10];
    const float* conv1_w   = (const float*)d_in[11];
    const float* conv1_b   = (const float*)d_in[12];
    const float* conv2_w   = (const float*)d_in[13];
    const float* conv2_b   = (const float*)d_in[14];

    float* out = (float*)d_out;
    float* fe = out;                             // 8*512*64 = 262144
    float* cw = out + Bn * T1n * En;             // 8*512*128 = 524288

    float* ws  = (float*)d_ws;
    float* xg  = ws;                             // 2*8*128*192 = 393216
    float* ctx = xg + 2 * Bn * T2n * Gn;         // 8*128*128  = 131072
    float* sC  = ctx + Bn * T2n * 128;           // 1024
    float* sL  = sC + Bn * T2n;                  // 4096
    float* Am  = sL + Bn * T1n;                  // 65536
    float* Bm  = Am + Bn * T2n * En;             // 65536
    float* Cm  = Bm + Bn * T2n * En;             // 65536

    int pre_blocks = 1024 + (Bn * T1n + 383) / 384 * (384 / 384) + 682;  // 1024 + 683
    pre_blocks = 1024 + (Bn * T1n / 6 + (Bn * T1n % 6 ? 1 : 0));         // exact: 1024+683
    k_pre <<<pre_blocks, 384, 0, stream>>>(char_seq, emb_table, Kf, bf, Kb, bb,
                                           lstm, w_char, xg, sL);
    k_scan<<<16, 64, 0, stream>>>(xg, Rf, bf, Rb, bb, char_seq, ctx);
    k_ctxw<<<Bn * T2n, 128, 0, stream>>>(ctx, conv1_w, conv2_w, w_char, Am, Bm, Cm, sC);
    k_final<<<(Bn * T1n) / 8, 128, 0, stream>>>(sL, sC, w_char, b_char, conv1_b,
                                                conv2_w, conv2_b, Am, Bm, Cm, fe, cw);
}